// Round 1
// baseline (92.395 us; speedup 1.0000x reference)
//
#include <hip/hip_runtime.h>
#include <hip/hip_bf16.h>
#include <math.h>

#define N 512
#define BIT 64
#define NUM_CLASSES 100
#define ALPHA 5.0f
#define LAM 1.0f

// ---------------------------------------------------------------------------
// prep: labels from one-hot y, zero accumulators, loss2 partial sum
// launch: 1 block x 512 threads (one thread per row)
// acc[0]=loss1_sum, acc[1]=valid_count, acc[2]=sum2
// ---------------------------------------------------------------------------
__global__ void prep_kernel(const float* __restrict__ u,
                            const float* __restrict__ y,
                            int* __restrict__ labels,
                            float* __restrict__ acc) {
    int tid = threadIdx.x;   // 0..511 == row
    if (tid < 4) acc[tid] = 0.0f;

    // label = argwhere(one_hot row)
    int lbl = 0;
    const float* yr = y + (size_t)tid * NUM_CLASSES;
    for (int c = 0; c < NUM_CLASSES; ++c) {
        if (yr[c] > 0.5f) lbl = c;
    }
    labels[tid] = lbl;

    // loss2 partial: sum over this row of (u - sign(u))^2
    float s = 0.0f;
    const float* ur = u + (size_t)tid * BIT;
    for (int k = 0; k < BIT; ++k) {
        float v = ur[k];
        float sg = (v > 0.0f) ? 1.0f : ((v < 0.0f) ? -1.0f : 0.0f);
        float d = v - sg;
        s += d * d;
    }
    // wave(64) reduce then one atomic per wave
    for (int off = 32; off > 0; off >>= 1) s += __shfl_down(s, off, 64);
    __syncthreads();                       // acc[2] is zeroed before atomics
    if ((tid & 63) == 0) atomicAdd(&acc[2], s);
}

// ---------------------------------------------------------------------------
// ip = u @ u^T  [N x N], LDS-tiled, 16x16 tile per block
// grid (32,32), block (16,16)
// ---------------------------------------------------------------------------
__global__ void ip_kernel(const float* __restrict__ u, float* __restrict__ ip) {
    __shared__ float As[16][BIT + 1];   // +1 pad: stride 65 breaks bank aliasing
    __shared__ float Bs[16][BIT + 1];
    int bx = blockIdx.x, by = blockIdx.y;
    int tx = threadIdx.x, ty = threadIdx.y;
    int tid = ty * 16 + tx;

    // 16 rows x 64 floats per tile, 256 threads -> 4 elements each
    for (int e = tid; e < 16 * BIT; e += 256) {
        int r = e >> 6;          // /64
        int c = e & 63;          // %64
        As[r][c] = u[((size_t)(by * 16 + r)) * BIT + c];
        Bs[r][c] = u[((size_t)(bx * 16 + r)) * BIT + c];
    }
    __syncthreads();

    float accv = 0.0f;
    #pragma unroll
    for (int k = 0; k < BIT; ++k) accv += As[ty][k] * Bs[tx][k];
    ip[((size_t)(by * 16 + ty)) * N + (bx * 16 + tx)] = accv;
}

// ---------------------------------------------------------------------------
// row: one block per row r. Sum over positives p, negatives n of
//   f = log1p(exp(clip(ip[r,p]-ip[r,n]-alpha, -100, 50))) - clip(...)
// then row_loss = sum / max(npos*nneg, 1); accumulate if valid.
// launch: 512 blocks x 256 threads
// ---------------------------------------------------------------------------
__global__ void row_kernel(const float* __restrict__ ip,
                           const int* __restrict__ labels,
                           float* __restrict__ acc) {
    int r = blockIdx.x;
    int tid = threadIdx.x;

    __shared__ float d[N];
    __shared__ int   lab[N];
    __shared__ int   poslist[N];
    __shared__ int   npos_s;
    __shared__ float wsum[4];

    if (tid == 0) npos_s = 0;
    for (int i = tid; i < N; i += 256) {
        d[i]   = ip[(size_t)r * N + i];
        lab[i] = labels[i];
    }
    __syncthreads();

    int lr = lab[r];
    for (int i = tid; i < N; i += 256) {
        if (lab[i] == lr) {
            int idx = atomicAdd(&npos_s, 1);
            poslist[idx] = i;
        }
    }
    __syncthreads();

    int npos = npos_s;
    int nneg = N - npos;

    float fsum = 0.0f;
    for (int pi = 0; pi < npos; ++pi) {
        float dp = d[poslist[pi]];
        for (int n = tid; n < N; n += 256) {
            if (lab[n] != lr) {
                float t = dp - d[n] - ALPHA;
                t = fminf(fmaxf(t, -100.0f), 50.0f);
                // f = log1p(exp(t)) - t == softplus(-t), numerically stable split
                float f = (t > 0.0f) ? log1pf(expf(-t))
                                     : (log1pf(expf(t)) - t);
                fsum += f;
            }
        }
    }

    // block reduce: wave64 shuffle, then 4 partials in LDS
    for (int off = 32; off > 0; off >>= 1) fsum += __shfl_down(fsum, off, 64);
    if ((tid & 63) == 0) wsum[tid >> 6] = fsum;
    __syncthreads();

    if (tid == 0) {
        float total = wsum[0] + wsum[1] + wsum[2] + wsum[3];
        bool valid = (npos > 0) && (nneg > 0);
        float pair_count = fmaxf((float)npos * (float)nneg, 1.0f);
        float row_loss = total / pair_count;
        if (valid) {
            atomicAdd(&acc[0], row_loss);
            atomicAdd(&acc[1], 1.0f);
        }
    }
}

// ---------------------------------------------------------------------------
// finish: combine
// ---------------------------------------------------------------------------
__global__ void finish_kernel(const float* __restrict__ acc,
                              float* __restrict__ out) {
    float count = acc[1];
    float loss1 = (count > 0.0f) ? (acc[0] / fmaxf(count, 1.0f)) : 0.0f;
    float loss2 = LAM * acc[2] / (float)(N * BIT);
    out[0] = loss1 + loss2;
}

extern "C" void kernel_launch(void* const* d_in, const int* in_sizes, int n_in,
                              void* d_out, int out_size, void* d_ws, size_t ws_size,
                              hipStream_t stream) {
    const float* u = (const float*)d_in[0];   // [512, 64]
    const float* y = (const float*)d_in[1];   // [512, 100]
    float* out = (float*)d_out;               // scalar

    // workspace layout
    char* ws = (char*)d_ws;
    float* ip     = (float*)ws;                                 // N*N*4 = 1 MiB
    int*   labels = (int*)(ws + (size_t)N * N * sizeof(float)); // 2 KiB
    float* acc    = (float*)(ws + (size_t)N * N * sizeof(float)
                                + (size_t)N * sizeof(int));     // 16 B

    prep_kernel<<<1, 512, 0, stream>>>(u, y, labels, acc);

    dim3 gb(N / 16, N / 16), tb(16, 16);
    ip_kernel<<<gb, tb, 0, stream>>>(u, ip);

    row_kernel<<<N, 256, 0, stream>>>(ip, labels, acc);

    finish_kernel<<<1, 1, 0, stream>>>(acc, out);
}